// Round 7
// baseline (167.867 us; speedup 1.0000x reference)
//
#include <hip/hip_runtime.h>
#include <cstdint>

typedef __attribute__((ext_vector_type(8))) short short8;
typedef __attribute__((ext_vector_type(4))) short short4x;
typedef __attribute__((ext_vector_type(4))) float floatx4;

__device__ __forceinline__ unsigned short f2b(float f) {
    unsigned int u = __builtin_bit_cast(unsigned int, f);
    u += 0x7fffu + ((u >> 16) & 1u);   // round-to-nearest-even
    return (unsigned short)(u >> 16);
}
__device__ __forceinline__ float b2f(unsigned short s) {
    unsigned int u = ((unsigned int)s) << 16;
    return __builtin_bit_cast(float, u);
}

#define GLDS(g, l) __builtin_amdgcn_global_load_lds(                                   \
    (const __attribute__((address_space(1))) unsigned int*)(g),                        \
    (__attribute__((address_space(3))) unsigned int*)(l), 16, 0, 0)

// ---------------- fused prep: x->bf16 cvt + both weight transposes ----------------
__global__ __launch_bounds__(256) void prep_kernel(const float* __restrict__ x,
                                                   unsigned short* __restrict__ xb,
                                                   const float* __restrict__ w1,
                                                   unsigned short* __restrict__ w1t,
                                                   const float* __restrict__ w2,
                                                   unsigned short* __restrict__ w2t) {
    __shared__ unsigned short tile[64][65];
    const int b = blockIdx.x, t = threadIdx.x;
    if (b < 1024) {
        for (int i = b * 256 + t; i < 1048576; i += 262144) {
            float4 v = ((const float4*)x)[i];
            ushort4 o;
            o.x = f2b(v.x); o.y = f2b(v.y); o.z = f2b(v.z); o.w = f2b(v.w);
            ((ushort4*)xb)[i] = o;
        }
        return;
    }
    const float* W; unsigned short* Wt; int K, N, kb, nb;
    if (b < 1792) { W = w1; Wt = w1t; K = 1024; N = 3072; kb = (b - 1024) & 15; nb = (b - 1024) >> 4; }
    else          { W = w2; Wt = w2t; K = 1024; N = 1024; kb = (b - 1792) & 15; nb = (b - 1792) >> 4; }
    const int k0 = kb * 64, n0 = nb * 64;
    for (int idx = t; idx < 64 * 64; idx += 256) {
        int i = idx >> 6, j = idx & 63;
        tile[j][i] = f2b(W[(size_t)(k0 + i) * N + n0 + j]);
    }
    __syncthreads();
    for (int idx = t; idx < 64 * 64; idx += 256) {
        int r = idx >> 6, c = idx & 63;
        Wt[(size_t)(n0 + r) * K + k0 + c] = tile[r][c];
    }
}

// ---------------- bf16 MFMA GEMM 128x128, GLDS double-buffer, 1 barrier/iter ----------------
// Blocks with colBase >= vSplit write their tile TRANSPOSED into vT[bh][d][s]
// (the qkv V-region is never read downstream); others store row-major into C.
__global__ __launch_bounds__(256) void gemm_bt_kernel(const unsigned short* __restrict__ A,
                                                      const unsigned short* __restrict__ Bt,
                                                      const float* __restrict__ bias,
                                                      unsigned short* __restrict__ C,
                                                      unsigned short* __restrict__ vTout,
                                                      int vSplit,
                                                      int M, int N, int K) {
    __shared__ unsigned short As[2][128][32];   // 16 KB
    __shared__ unsigned short Bs[2][128][32];   // 16 KB

    const int t = threadIdx.x;
    const int wave = t >> 6, lane = t & 63;
    const int quad = lane >> 4, l16 = lane & 15;
    const int rowBase = blockIdx.x * 128;
    const int colBase = blockIdx.y * 128;
    const int waveM = (wave >> 1) * 64;
    const int waveN = (wave & 1) * 64;

    floatx4 acc[4][4];
#pragma unroll
    for (int i = 0; i < 4; ++i)
#pragma unroll
        for (int j = 0; j < 4; ++j) acc[i][j] = (floatx4){0.f, 0.f, 0.f, 0.f};

    const int r0 = t >> 2, cc0 = (t & 3) * 8;
    const int r1 = 64 + (t >> 2);
    const unsigned short* aBase = A + (size_t)rowBase * K;
    const unsigned short* bBase = Bt + (size_t)colBase * K;

    auto stage = [&](int kk, int bf) {
        const int k0 = kk * 32;
        GLDS(aBase + (size_t)r0 * K + k0 + cc0, &As[bf][r0][cc0]);
        GLDS(aBase + (size_t)r1 * K + k0 + cc0, &As[bf][r1][cc0]);
        GLDS(bBase + (size_t)r0 * K + k0 + cc0, &Bs[bf][r0][cc0]);
        GLDS(bBase + (size_t)r1 * K + k0 + cc0, &Bs[bf][r1][cc0]);
    };

    const int nIter = K >> 5;
    stage(0, 0);

    for (int kk = 0; kk < nIter; ++kk) {
        __syncthreads();                                   // tile kk landed (in flight a full iter)
        if (kk + 1 < nIter) stage(kk + 1, (kk + 1) & 1);   // prefetch next into other buffer
        const int buf = kk & 1;

        short8 af[4], bf[4];
#pragma unroll
        for (int mi = 0; mi < 4; ++mi)
            af[mi] = *(const short8*)&As[buf][waveM + mi * 16 + l16][quad * 8];
#pragma unroll
        for (int ni = 0; ni < 4; ++ni)
            bf[ni] = *(const short8*)&Bs[buf][waveN + ni * 16 + l16][quad * 8];
#pragma unroll
        for (int mi = 0; mi < 4; ++mi)
#pragma unroll
            for (int ni = 0; ni < 4; ++ni)
                acc[mi][ni] = __builtin_amdgcn_mfma_f32_16x16x32_bf16(af[mi], bf[ni], acc[mi][ni], 0, 0, 0);
    }

    if (colBase >= vSplit) {
        // ---- V mode: transposed store to vT[bh][d][s]; each 128B line of vT is
        // fully covered by this block (s covers 128 consecutive values) ----
#pragma unroll
        for (int mi = 0; mi < 4; ++mi)
#pragma unroll
            for (int ni = 0; ni < 4; ++ni) {
                int col = colBase + waveN + ni * 16 + l16 - vSplit;  // h*64+d
                float bv = bias[colBase + waveN + ni * 16 + l16];
#pragma unroll
                for (int r = 0; r < 4; ++r) {
                    int row = rowBase + waveM + mi * 16 + quad * 4 + r;  // b*1024+s
                    vTout[((size_t)((row >> 10) * 16 + (col >> 6)) * 64 + (col & 63)) * 1024
                          + (row & 1023)] = f2b(acc[mi][ni][r] + bv);
                }
            }
    } else {
#pragma unroll
        for (int mi = 0; mi < 4; ++mi)
#pragma unroll
            for (int ni = 0; ni < 4; ++ni) {
                int col = colBase + waveN + ni * 16 + l16;
                float bv = bias[col];
#pragma unroll
                for (int r = 0; r < 4; ++r) {
                    int row = rowBase + waveM + mi * 16 + quad * 4 + r;
                    C[(size_t)row * N + col] = f2b(acc[mi][ni][r] + bv);
                }
            }
    }
}

// ---------------- fp32-out GEMM 64x64 tiles (grid 1024 = 4 blocks/CU), GLDS dbuf ----------------
__global__ __launch_bounds__(256) void gemm2_kernel(const unsigned short* __restrict__ A,
                                                    const unsigned short* __restrict__ Bt,
                                                    const float* __restrict__ bias,
                                                    float* __restrict__ C,
                                                    int M, int N, int K) {
    __shared__ unsigned short As[2][64][32];   // 8 KB
    __shared__ unsigned short Bs[2][64][32];   // 8 KB

    const int t = threadIdx.x;
    const int wave = t >> 6, lane = t & 63;
    const int quad = lane >> 4, l16 = lane & 15;
    const int rowBase = blockIdx.x * 64;
    const int colBase = blockIdx.y * 64;
    const int waveM = (wave >> 1) * 32;
    const int waveN = (wave & 1) * 32;

    floatx4 acc[2][2];
#pragma unroll
    for (int i = 0; i < 2; ++i)
#pragma unroll
        for (int j = 0; j < 2; ++j) acc[i][j] = (floatx4){0.f, 0.f, 0.f, 0.f};

    const int r0 = t >> 2, cc0 = (t & 3) * 8;
    const unsigned short* aBase = A + (size_t)rowBase * K;
    const unsigned short* bBase = Bt + (size_t)colBase * K;

    auto stage = [&](int kk, int bf) {
        const int k0 = kk * 32;
        GLDS(aBase + (size_t)r0 * K + k0 + cc0, &As[bf][r0][cc0]);
        GLDS(bBase + (size_t)r0 * K + k0 + cc0, &Bs[bf][r0][cc0]);
    };

    const int nIter = K >> 5;
    stage(0, 0);

    for (int kk = 0; kk < nIter; ++kk) {
        __syncthreads();
        if (kk + 1 < nIter) stage(kk + 1, (kk + 1) & 1);
        const int buf = kk & 1;

        short8 af[2], bf[2];
#pragma unroll
        for (int mi = 0; mi < 2; ++mi)
            af[mi] = *(const short8*)&As[buf][waveM + mi * 16 + l16][quad * 8];
#pragma unroll
        for (int ni = 0; ni < 2; ++ni)
            bf[ni] = *(const short8*)&Bs[buf][waveN + ni * 16 + l16][quad * 8];
#pragma unroll
        for (int mi = 0; mi < 2; ++mi)
#pragma unroll
            for (int ni = 0; ni < 2; ++ni)
                acc[mi][ni] = __builtin_amdgcn_mfma_f32_16x16x32_bf16(af[mi], bf[ni], acc[mi][ni], 0, 0, 0);
    }

#pragma unroll
    for (int mi = 0; mi < 2; ++mi)
#pragma unroll
        for (int ni = 0; ni < 2; ++ni) {
            int col = colBase + waveN + ni * 16 + l16;
            float bv = bias[col];
#pragma unroll
            for (int r = 0; r < 4; ++r) {
                int row = rowBase + waveM + mi * 16 + quad * 4 + r;
                C[(size_t)row * N + col] = acc[mi][ni][r] + bv;
            }
        }
}

// ---------------- fused causal flash attention (validated R4/R6 structure) ----------------
// Q pre-scaled by log2e/8 so softmax uses native exp2.
__global__ __launch_bounds__(256) void attn_kernel(const unsigned short* __restrict__ qkv,
                                                   const unsigned short* __restrict__ vT,
                                                   unsigned short* __restrict__ aout) {
    __shared__ unsigned short Ks[2 * 64 * 64];
    __shared__ unsigned short Vs[2 * 64 * 64];
    __shared__ unsigned short Tb[4][16 * 72];

    const int p  = blockIdx.x;
    const int bh = blockIdx.y;
    const int b = bh >> 4, h = bh & 15;
    const int qb1 = p, qb2 = 15 - p;
    const int t = threadIdx.x;
    const int wave = t >> 6, lane = t & 63;
    const int quad = lane >> 4, l16 = lane & 15;
    const int h7 = l16 & 7;

    const size_t rowB = (size_t)b * 1024;
    const size_t hoff = (size_t)h * 64;
    const int qA0 = qb1 * 64 + wave * 16;
    const int qB0 = qb2 * 64 + wave * 16;

    const float qscale = 0.125f * 1.44269504f;   // fold softmax scale + log2e into Q
    short8 qfA[2], qfB[2];
#pragma unroll
    for (int kc = 0; kc < 2; ++kc) {
        short8 qa = *(const short8*)(qkv + (rowB + qA0 + l16) * 3072 + hoff + kc * 32 + quad * 8);
        short8 qb = *(const short8*)(qkv + (rowB + qB0 + l16) * 3072 + hoff + kc * 32 + quad * 8);
#pragma unroll
        for (int e = 0; e < 8; ++e) {
            qa[e] = (short)f2b(b2f((unsigned short)qa[e]) * qscale);
            qb[e] = (short)f2b(b2f((unsigned short)qb[e]) * qscale);
        }
        qfA[kc] = qa; qfB[kc] = qb;
    }

    const int lr = lane >> 3;
    const int sc8 = (lane & 7) * 8;
    const int gc8 = ((lane & 7) ^ lr) * 8;
    const unsigned short* kSrc = qkv + rowB * 3072 + hoff + 1024;
    const unsigned short* vSrc = vT + (size_t)bh * 65536;

    auto stage = [&](int kt, int bf) {
        const unsigned short* kp = kSrc + (size_t)kt * 64 * 3072;
        const unsigned short* vp = vSrc + kt * 64;
        int r0 = wave * 16 + lr, r1 = r0 + 8;
        GLDS(kp + (size_t)r0 * 3072 + gc8, &Ks[bf * 4096 + r0 * 64 + sc8]);
        GLDS(kp + (size_t)r1 * 3072 + gc8, &Ks[bf * 4096 + r1 * 64 + sc8]);
        GLDS(vp + (size_t)r0 * 1024 + gc8, &Vs[bf * 4096 + r0 * 64 + sc8]);
        GLDS(vp + (size_t)r1 * 1024 + gc8, &Vs[bf * 4096 + r1 * 64 + sc8]);
    };

    float lpA = 0.f, lpB = 0.f;
    floatx4 oA[4], oB[4];
#pragma unroll
    for (int ni = 0; ni < 4; ++ni) {
        oA[ni] = (floatx4){0.f, 0.f, 0.f, 0.f};
        oB[ni] = (floatx4){0.f, 0.f, 0.f, 0.f};
    }

    const int nT = qb2 + 1;
    stage(0, 0);

    for (int kt = 0; kt < nT; ++kt) {
        __syncthreads();
        if (kt + 1 < nT) stage(kt + 1, (kt + 1) & 1);
        const int kb = (kt & 1) * 4096;

        short8 kf[4][2];
#pragma unroll
        for (int jn = 0; jn < 4; ++jn)
#pragma unroll
            for (int kc = 0; kc < 2; ++kc)
                kf[jn][kc] = *(const short8*)&Ks[kb + (jn * 16 + l16) * 64 + (((kc * 4 + quad) ^ h7) * 8)];

        short4x vf[4][4];
#pragma unroll
        for (int ni = 0; ni < 4; ++ni)
#pragma unroll
            for (int jb = 0; jb < 4; ++jb)
                vf[ni][jb] = *(const short4x*)&Vs[kb + (ni * 16 + l16) * 64 +
                                                 (((jb * 2 + (quad >> 1)) ^ h7) * 8) + (quad & 1) * 4];

        auto qtile = [&](short8 (&qf)[2], floatx4 (&o)[4], float& lp, bool diag) {
            floatx4 s[4];
#pragma unroll
            for (int jn = 0; jn < 4; ++jn) s[jn] = (floatx4){0.f, 0.f, 0.f, 0.f};
#pragma unroll
            for (int jn = 0; jn < 4; ++jn)
#pragma unroll
                for (int kc = 0; kc < 2; ++kc)
                    s[jn] = __builtin_amdgcn_mfma_f32_16x16x32_bf16(kf[jn][kc], qf[kc], s[jn], 0, 0, 0);
            if (diag) {
                int ql = wave * 16 + l16;
#pragma unroll
                for (int jn = 0; jn < 4; ++jn)
#pragma unroll
                    for (int r = 0; r < 4; ++r)
                        if (jn * 16 + quad * 4 + r > ql) s[jn][r] = -1e30f;
            }
            short4x pb[4];
#pragma unroll
            for (int jb = 0; jb < 4; ++jb)
#pragma unroll
                for (int r = 0; r < 4; ++r) {
                    float pe = exp2f(s[jb][r]);      // native v_exp_f32; masked -> 0
                    lp += pe;
                    pb[jb][r] = (short)f2b(pe);
                }
#pragma unroll
            for (int jb = 0; jb < 4; ++jb)
#pragma unroll
                for (int ni = 0; ni < 4; ++ni)
                    o[ni] = __builtin_amdgcn_mfma_f32_16x16x16bf16_1k(vf[ni][jb], pb[jb], o[ni], 0, 0, 0);
        };

        qtile(qfB, oB, lpB, kt == qb2);
        if (kt <= qb1) qtile(qfA, oA, lpA, kt == qb1);
    }

    lpA += __shfl_xor(lpA, 16); lpA += __shfl_xor(lpA, 32);
    lpB += __shfl_xor(lpB, 16); lpB += __shfl_xor(lpB, 32);
    const float liA = 1.f / lpA, liB = 1.f / lpB;

    auto writeOut = [&](floatx4 (&o)[4], float li, int q0) {
#pragma unroll
        for (int ni = 0; ni < 4; ++ni)
#pragma unroll
            for (int r = 0; r < 4; ++r)
                Tb[wave][l16 * 72 + ni * 16 + quad * 4 + r] = f2b(o[ni][r] * li);
#pragma unroll
        for (int i = 0; i < 2; ++i) {
            int q = lane >> 2, c = (lane & 3) + 4 * i;
            short8 v = *(const short8*)&Tb[wave][q * 72 + c * 8];
            *(short8*)(aout + (rowB + q0 + q) * 1024 + hoff + c * 8) = v;
        }
    };
    writeOut(oA, liA, qA0);
    writeOut(oB, liB, qB0);
}

extern "C" void kernel_launch(void* const* d_in, const int* in_sizes, int n_in,
                              void* d_out, int out_size, void* d_ws, size_t ws_size,
                              hipStream_t stream) {
    const float* x  = (const float*)d_in[0];
    const float* w1 = (const float*)d_in[1];
    const float* b1 = (const float*)d_in[2];
    const float* w2 = (const float*)d_in[3];
    const float* b2 = (const float*)d_in[4];
    float* out = (float*)d_out;

    unsigned short* xb   = (unsigned short*)d_ws;              // 8 MB
    unsigned short* w1t  = xb  + (size_t)4096 * 1024;          // 6 MB  [3072,1024]
    unsigned short* w2t  = w1t + (size_t)3072 * 1024;          // 2 MB  [1024,1024]
    unsigned short* qkv  = w2t + (size_t)1024 * 1024;          // 24 MB [4096,3072] (V third unused)
    unsigned short* attn = qkv + (size_t)4096 * 3072;          // 8 MB  [4096,1024]
    unsigned short* vTb  = attn + (size_t)4096 * 1024;         // 8 MB  [64,64,1024]

    prep_kernel<<<2048, 256, 0, stream>>>(x, xb, w1, w1t, w2, w2t);
    gemm_bt_kernel<<<dim3(32, 24), 256, 0, stream>>>(xb, w1t, b1, qkv, vTb, 2048,
                                                     4096, 3072, 1024);
    attn_kernel<<<dim3(8, 64), 256, 0, stream>>>(qkv, vTb, attn);
    gemm2_kernel<<<dim3(64, 16), 256, 0, stream>>>(attn, w2t, b2, out, 4096, 1024, 1024);
}

// Round 8
// 162.792 us; speedup vs baseline: 1.0312x; 1.0312x over previous
//
#include <hip/hip_runtime.h>
#include <cstdint>

typedef __attribute__((ext_vector_type(8))) short short8;
typedef __attribute__((ext_vector_type(4))) short short4x;
typedef __attribute__((ext_vector_type(4))) float floatx4;

__device__ __forceinline__ unsigned short f2b(float f) {
    unsigned int u = __builtin_bit_cast(unsigned int, f);
    u += 0x7fffu + ((u >> 16) & 1u);   // round-to-nearest-even
    return (unsigned short)(u >> 16);
}
__device__ __forceinline__ float b2f(unsigned short s) {
    unsigned int u = ((unsigned int)s) << 16;
    return __builtin_bit_cast(float, u);
}
__device__ __forceinline__ float fast_exp2(float x) {
    float r;
    asm("v_exp_f32 %0, %1" : "=v"(r) : "v"(x));
    return r;
}
// pack trunc-bf16(lo), trunc-bf16(hi) into one uint via v_perm_b32
__device__ __forceinline__ unsigned int pack_bf16_trunc(float lo, float hi) {
    return __builtin_amdgcn_perm(__builtin_bit_cast(unsigned int, hi),
                                 __builtin_bit_cast(unsigned int, lo), 0x07060302u);
}

#define GLDS(g, l) __builtin_amdgcn_global_load_lds(                                   \
    (const __attribute__((address_space(1))) unsigned int*)(g),                        \
    (__attribute__((address_space(3))) unsigned int*)(l), 16, 0, 0)

// ---------------- fused prep: x->bf16 cvt + both weight transposes ----------------
__global__ __launch_bounds__(256) void prep_kernel(const float* __restrict__ x,
                                                   unsigned short* __restrict__ xb,
                                                   const float* __restrict__ w1,
                                                   unsigned short* __restrict__ w1t,
                                                   const float* __restrict__ w2,
                                                   unsigned short* __restrict__ w2t) {
    __shared__ unsigned short tile[64][65];
    const int b = blockIdx.x, t = threadIdx.x;
    if (b < 1024) {
        for (int i = b * 256 + t; i < 1048576; i += 262144) {
            float4 v = ((const float4*)x)[i];
            ushort4 o;
            o.x = f2b(v.x); o.y = f2b(v.y); o.z = f2b(v.z); o.w = f2b(v.w);
            ((ushort4*)xb)[i] = o;
        }
        return;
    }
    const float* W; unsigned short* Wt; int K, N, kb, nb;
    if (b < 1792) { W = w1; Wt = w1t; K = 1024; N = 3072; kb = (b - 1024) & 15; nb = (b - 1024) >> 4; }
    else          { W = w2; Wt = w2t; K = 1024; N = 1024; kb = (b - 1792) & 15; nb = (b - 1792) >> 4; }
    const int k0 = kb * 64, n0 = nb * 64;
    for (int idx = t; idx < 64 * 64; idx += 256) {
        int i = idx >> 6, j = idx & 63;
        tile[j][i] = f2b(W[(size_t)(k0 + i) * N + n0 + j]);
    }
    __syncthreads();
    for (int idx = t; idx < 64 * 64; idx += 256) {
        int r = idx >> 6, c = idx & 63;
        Wt[(size_t)(n0 + r) * K + k0 + c] = tile[r][c];
    }
}

// ---------------- bf16 MFMA GEMM 128x128, GLDS double-buffer, 1 barrier/iter ----------------
// Blocks with colBase >= vSplit write their tile TRANSPOSED into vT[bh][d][s].
__global__ __launch_bounds__(256) void gemm_bt_kernel(const unsigned short* __restrict__ A,
                                                      const unsigned short* __restrict__ Bt,
                                                      const float* __restrict__ bias,
                                                      unsigned short* __restrict__ C,
                                                      unsigned short* __restrict__ vTout,
                                                      int vSplit,
                                                      int M, int N, int K) {
    __shared__ unsigned short As[2][128][32];   // 16 KB
    __shared__ unsigned short Bs[2][128][32];   // 16 KB

    const int t = threadIdx.x;
    const int wave = t >> 6, lane = t & 63;
    const int quad = lane >> 4, l16 = lane & 15;
    const int rowBase = blockIdx.x * 128;
    const int colBase = blockIdx.y * 128;
    const int waveM = (wave >> 1) * 64;
    const int waveN = (wave & 1) * 64;

    floatx4 acc[4][4];
#pragma unroll
    for (int i = 0; i < 4; ++i)
#pragma unroll
        for (int j = 0; j < 4; ++j) acc[i][j] = (floatx4){0.f, 0.f, 0.f, 0.f};

    const int r0 = t >> 2, cc0 = (t & 3) * 8;
    const int r1 = 64 + (t >> 2);
    const unsigned short* aBase = A + (size_t)rowBase * K;
    const unsigned short* bBase = Bt + (size_t)colBase * K;

    auto stage = [&](int kk, int bf) {
        const int k0 = kk * 32;
        GLDS(aBase + (size_t)r0 * K + k0 + cc0, &As[bf][r0][cc0]);
        GLDS(aBase + (size_t)r1 * K + k0 + cc0, &As[bf][r1][cc0]);
        GLDS(bBase + (size_t)r0 * K + k0 + cc0, &Bs[bf][r0][cc0]);
        GLDS(bBase + (size_t)r1 * K + k0 + cc0, &Bs[bf][r1][cc0]);
    };

    const int nIter = K >> 5;
    stage(0, 0);

    for (int kk = 0; kk < nIter; ++kk) {
        __syncthreads();
        if (kk + 1 < nIter) stage(kk + 1, (kk + 1) & 1);
        const int buf = kk & 1;

        short8 af[4], bf[4];
#pragma unroll
        for (int mi = 0; mi < 4; ++mi)
            af[mi] = *(const short8*)&As[buf][waveM + mi * 16 + l16][quad * 8];
#pragma unroll
        for (int ni = 0; ni < 4; ++ni)
            bf[ni] = *(const short8*)&Bs[buf][waveN + ni * 16 + l16][quad * 8];
#pragma unroll
        for (int mi = 0; mi < 4; ++mi)
#pragma unroll
            for (int ni = 0; ni < 4; ++ni)
                acc[mi][ni] = __builtin_amdgcn_mfma_f32_16x16x32_bf16(af[mi], bf[ni], acc[mi][ni], 0, 0, 0);
    }

    if (colBase >= vSplit) {
#pragma unroll
        for (int mi = 0; mi < 4; ++mi)
#pragma unroll
            for (int ni = 0; ni < 4; ++ni) {
                int col = colBase + waveN + ni * 16 + l16 - vSplit;  // h*64+d
                float bv = bias[colBase + waveN + ni * 16 + l16];
#pragma unroll
                for (int r = 0; r < 4; ++r) {
                    int row = rowBase + waveM + mi * 16 + quad * 4 + r;  // b*1024+s
                    vTout[((size_t)((row >> 10) * 16 + (col >> 6)) * 64 + (col & 63)) * 1024
                          + (row & 1023)] = f2b(acc[mi][ni][r] + bv);
                }
            }
    } else {
#pragma unroll
        for (int mi = 0; mi < 4; ++mi)
#pragma unroll
            for (int ni = 0; ni < 4; ++ni) {
                int col = colBase + waveN + ni * 16 + l16;
                float bv = bias[col];
#pragma unroll
                for (int r = 0; r < 4; ++r) {
                    int row = rowBase + waveM + mi * 16 + quad * 4 + r;
                    C[(size_t)row * N + col] = f2b(acc[mi][ni][r] + bv);
                }
            }
    }
}

// ---------------- fp32-out GEMM 128x64 tiles (grid 512, 2/CU), GLDS dbuf ----------------
__global__ __launch_bounds__(256) void gemm2_kernel(const unsigned short* __restrict__ A,
                                                    const unsigned short* __restrict__ Bt,
                                                    const float* __restrict__ bias,
                                                    float* __restrict__ C,
                                                    int M, int N, int K) {
    __shared__ unsigned short As[2][128][32];   // 16 KB
    __shared__ unsigned short Bs[2][64][32];    // 8 KB

    const int t = threadIdx.x;
    const int wave = t >> 6, lane = t & 63;
    const int quad = lane >> 4, l16 = lane & 15;
    const int rowBase = blockIdx.x * 128;
    const int colBase = blockIdx.y * 64;
    const int waveM = (wave >> 1) * 64;
    const int waveN = (wave & 1) * 32;

    floatx4 acc[4][2];
#pragma unroll
    for (int i = 0; i < 4; ++i)
#pragma unroll
        for (int j = 0; j < 2; ++j) acc[i][j] = (floatx4){0.f, 0.f, 0.f, 0.f};

    const int r0 = t >> 2, cc0 = (t & 3) * 8;
    const int r1 = 64 + (t >> 2);
    const unsigned short* aBase = A + (size_t)rowBase * K;
    const unsigned short* bBase = Bt + (size_t)colBase * K;

    auto stage = [&](int kk, int bf) {
        const int k0 = kk * 32;
        GLDS(aBase + (size_t)r0 * K + k0 + cc0, &As[bf][r0][cc0]);
        GLDS(aBase + (size_t)r1 * K + k0 + cc0, &As[bf][r1][cc0]);
        GLDS(bBase + (size_t)r0 * K + k0 + cc0, &Bs[bf][r0][cc0]);
    };

    const int nIter = K >> 5;
    stage(0, 0);

    for (int kk = 0; kk < nIter; ++kk) {
        __syncthreads();
        if (kk + 1 < nIter) stage(kk + 1, (kk + 1) & 1);
        const int buf = kk & 1;

        short8 af[4], bf[2];
#pragma unroll
        for (int mi = 0; mi < 4; ++mi)
            af[mi] = *(const short8*)&As[buf][waveM + mi * 16 + l16][quad * 8];
#pragma unroll
        for (int ni = 0; ni < 2; ++ni)
            bf[ni] = *(const short8*)&Bs[buf][waveN + ni * 16 + l16][quad * 8];
#pragma unroll
        for (int mi = 0; mi < 4; ++mi)
#pragma unroll
            for (int ni = 0; ni < 2; ++ni)
                acc[mi][ni] = __builtin_amdgcn_mfma_f32_16x16x32_bf16(af[mi], bf[ni], acc[mi][ni], 0, 0, 0);
    }

#pragma unroll
    for (int mi = 0; mi < 4; ++mi)
#pragma unroll
        for (int ni = 0; ni < 2; ++ni) {
            int col = colBase + waveN + ni * 16 + l16;
            float bv = bias[col];
#pragma unroll
            for (int r = 0; r < 4; ++r) {
                int row = rowBase + waveM + mi * 16 + quad * 4 + r;
                C[(size_t)row * N + col] = acc[mi][ni][r] + bv;
            }
        }
}

// ---------------- fused causal flash attention, 2 kv-tiles per barrier ----------------
// S^T = K.Q^T (A=K, B=Q); P^T register-resident; O^T = V^T.P^T. Paired q-tiles
// (p, 15-p) share the K/V stream. Two kv-tiles staged per barrier (32 KB window
// > HBM latency). exp via raw v_exp_f32; P packed via v_perm truncation.
__global__ __launch_bounds__(256) void attn_kernel(const unsigned short* __restrict__ qkv,
                                                   const unsigned short* __restrict__ vT,
                                                   unsigned short* __restrict__ aout) {
    __shared__ unsigned short Ks[2][2][4096];   // [buf][slot][kv*64+d swizzled]  32 KB
    __shared__ unsigned short Vs[2][2][4096];   // 32 KB
    __shared__ unsigned short Tb[4][16 * 72];   // 9 KB

    const int p  = blockIdx.x;
    const int bh = blockIdx.y;
    const int b = bh >> 4, h = bh & 15;
    const int qb1 = p, qb2 = 15 - p;
    const int t = threadIdx.x;
    const int wave = t >> 6, lane = t & 63;
    const int quad = lane >> 4, l16 = lane & 15;
    const int h7 = l16 & 7;

    const size_t rowB = (size_t)b * 1024;
    const size_t hoff = (size_t)h * 64;
    const int qA0 = qb1 * 64 + wave * 16;
    const int qB0 = qb2 * 64 + wave * 16;

    const float qscale = 0.125f * 1.44269504f;   // fold softmax scale + log2e into Q
    short8 qfA[2], qfB[2];
#pragma unroll
    for (int kc = 0; kc < 2; ++kc) {
        short8 qa = *(const short8*)(qkv + (rowB + qA0 + l16) * 3072 + hoff + kc * 32 + quad * 8);
        short8 qb = *(const short8*)(qkv + (rowB + qB0 + l16) * 3072 + hoff + kc * 32 + quad * 8);
#pragma unroll
        for (int e = 0; e < 8; ++e) {
            qa[e] = (short)f2b(b2f((unsigned short)qa[e]) * qscale);
            qb[e] = (short)f2b(b2f((unsigned short)qb[e]) * qscale);
        }
        qfA[kc] = qa; qfB[kc] = qb;
    }

    const int lr = lane >> 3;
    const int sc8 = (lane & 7) * 8;
    const int gc8 = ((lane & 7) ^ lr) * 8;
    const unsigned short* kSrc = qkv + rowB * 3072 + hoff + 1024;
    const unsigned short* vSrc = vT + (size_t)bh * 65536;

    auto stageT = [&](int kt, int bf, int sl) {
        const unsigned short* kp = kSrc + (size_t)kt * 64 * 3072;
        const unsigned short* vp = vSrc + kt * 64;
        int r0 = wave * 16 + lr, r1 = r0 + 8;
        GLDS(kp + (size_t)r0 * 3072 + gc8, &Ks[bf][sl][r0 * 64 + sc8]);
        GLDS(kp + (size_t)r1 * 3072 + gc8, &Ks[bf][sl][r1 * 64 + sc8]);
        GLDS(vp + (size_t)r0 * 1024 + gc8, &Vs[bf][sl][r0 * 64 + sc8]);
        GLDS(vp + (size_t)r1 * 1024 + gc8, &Vs[bf][sl][r1 * 64 + sc8]);
    };

    float lpA = 0.f, lpB = 0.f;
    floatx4 oA[4], oB[4];
#pragma unroll
    for (int ni = 0; ni < 4; ++ni) {
        oA[ni] = (floatx4){0.f, 0.f, 0.f, 0.f};
        oB[ni] = (floatx4){0.f, 0.f, 0.f, 0.f};
    }

    const int nT = qb2 + 1;            // 9..16 kv-tiles
    const int nP = (nT + 1) >> 1;      // barrier steps

    auto doTile = [&](int kt, const unsigned short* Kb, const unsigned short* Vb) {
        short8 kf[4][2];
#pragma unroll
        for (int jn = 0; jn < 4; ++jn)
#pragma unroll
            for (int kc = 0; kc < 2; ++kc)
                kf[jn][kc] = *(const short8*)&Kb[(jn * 16 + l16) * 64 + (((kc * 4 + quad) ^ h7) * 8)];
        short4x vf[4][4];
#pragma unroll
        for (int ni = 0; ni < 4; ++ni)
#pragma unroll
            for (int jb = 0; jb < 4; ++jb)
                vf[ni][jb] = *(const short4x*)&Vb[(ni * 16 + l16) * 64 +
                                                 (((jb * 2 + (quad >> 1)) ^ h7) * 8) + (quad & 1) * 4];

        auto qtile = [&](short8 (&qf)[2], floatx4 (&o)[4], float& lp, bool diag) {
            floatx4 s[4];
#pragma unroll
            for (int jn = 0; jn < 4; ++jn) s[jn] = (floatx4){0.f, 0.f, 0.f, 0.f};
#pragma unroll
            for (int jn = 0; jn < 4; ++jn)
#pragma unroll
                for (int kc = 0; kc < 2; ++kc)
                    s[jn] = __builtin_amdgcn_mfma_f32_16x16x32_bf16(kf[jn][kc], qf[kc], s[jn], 0, 0, 0);
            if (diag) {
                int ql = wave * 16 + l16;
#pragma unroll
                for (int jn = 0; jn < 4; ++jn)
#pragma unroll
                    for (int r = 0; r < 4; ++r)
                        if (jn * 16 + quad * 4 + r > ql) s[jn][r] = -1e30f;
            }
            short4x pb[4];
#pragma unroll
            for (int jb = 0; jb < 4; ++jb) {
                float pe0 = fast_exp2(s[jb][0]);
                float pe1 = fast_exp2(s[jb][1]);
                float pe2 = fast_exp2(s[jb][2]);
                float pe3 = fast_exp2(s[jb][3]);
                lp += (pe0 + pe1) + (pe2 + pe3);
                uint2 u;
                u.x = pack_bf16_trunc(pe0, pe1);
                u.y = pack_bf16_trunc(pe2, pe3);
                pb[jb] = __builtin_bit_cast(short4x, u);
            }
#pragma unroll
            for (int jb = 0; jb < 4; ++jb)
#pragma unroll
                for (int ni = 0; ni < 4; ++ni)
                    o[ni] = __builtin_amdgcn_mfma_f32_16x16x16bf16_1k(vf[ni][jb], pb[jb], o[ni], 0, 0, 0);
        };

        qtile(qfB, oB, lpB, kt == qb2);
        if (kt <= qb1) qtile(qfA, oA, lpA, kt == qb1);
    };

    stageT(0, 0, 0);
    stageT(1, 0, 1);                   // nT >= 9, always valid

    for (int pi = 0; pi < nP; ++pi) {
        __syncthreads();               // pair pi staged
        if (pi + 1 < nP) {             // prefetch next pair (in flight across 2-tile compute)
            stageT(2 * pi + 2, (pi + 1) & 1, 0);
            if (2 * pi + 3 < nT) stageT(2 * pi + 3, (pi + 1) & 1, 1);
        }
        const int bfI = pi & 1;
        doTile(2 * pi, &Ks[bfI][0][0], &Vs[bfI][0][0]);
        if (2 * pi + 1 < nT) doTile(2 * pi + 1, &Ks[bfI][1][0], &Vs[bfI][1][0]);
    }

    lpA += __shfl_xor(lpA, 16); lpA += __shfl_xor(lpA, 32);
    lpB += __shfl_xor(lpB, 16); lpB += __shfl_xor(lpB, 32);
    const float liA = 1.f / lpA, liB = 1.f / lpB;

    auto writeOut = [&](floatx4 (&o)[4], float li, int q0) {
#pragma unroll
        for (int ni = 0; ni < 4; ++ni)
#pragma unroll
            for (int r = 0; r < 4; ++r)
                Tb[wave][l16 * 72 + ni * 16 + quad * 4 + r] = f2b(o[ni][r] * li);
#pragma unroll
        for (int i = 0; i < 2; ++i) {
            int q = lane >> 2, c = (lane & 3) + 4 * i;
            short8 v = *(const short8*)&Tb[wave][q * 72 + c * 8];
            *(short8*)(aout + (rowB + q0 + q) * 1024 + hoff + c * 8) = v;
        }
    };
    writeOut(oA, liA, qA0);
    writeOut(oB, liB, qB0);
}

extern "C" void kernel_launch(void* const* d_in, const int* in_sizes, int n_in,
                              void* d_out, int out_size, void* d_ws, size_t ws_size,
                              hipStream_t stream) {
    const float* x  = (const float*)d_in[0];
    const float* w1 = (const float*)d_in[1];
    const float* b1 = (const float*)d_in[2];
    const float* w2 = (const float*)d_in[3];
    const float* b2 = (const float*)d_in[4];
    float* out = (float*)d_out;

    unsigned short* xb   = (unsigned short*)d_ws;              // 8 MB
    unsigned short* w1t  = xb  + (size_t)4096 * 1024;          // 6 MB  [3072,1024]
    unsigned short* w2t  = w1t + (size_t)3072 * 1024;          // 2 MB  [1024,1024]
    unsigned short* qkv  = w2t + (size_t)1024 * 1024;          // 24 MB [4096,3072] (V third unused)
    unsigned short* attn = qkv + (size_t)4096 * 3072;          // 8 MB  [4096,1024]
    unsigned short* vTb  = attn + (size_t)4096 * 1024;         // 8 MB  [64,64,1024]

    prep_kernel<<<2048, 256, 0, stream>>>(x, xb, w1, w1t, w2, w2t);
    gemm_bt_kernel<<<dim3(32, 24), 256, 0, stream>>>(xb, w1t, b1, qkv, vTb, 2048,
                                                     4096, 3072, 1024);
    attn_kernel<<<dim3(8, 64), 256, 0, stream>>>(qkv, vTb, attn);
    gemm2_kernel<<<dim3(32, 16), 256, 0, stream>>>(attn, w2t, b2, out, 4096, 1024, 1024);
}